// Round 10
// baseline (276.175 us; speedup 1.0000x reference)
//
#include <hip/hip_runtime.h>
#include <hip/hip_bf16.h>

// R10: LDS-free maxsim. A (sat) fragments loaded straight from L2 into VGPRs
// (same fragment addressing as the verified LDS path), B (pano) in VGPRs,
// zero barriers, double-buffered half-tiles, compiler-counted vmcnt.
// Kernel body repeated REP=6x (idempotent) so the dispatch exceeds the ~40us
// harness fills and appears in rocprof top-5 with counters.
//
// out[a,b] = sum_i max_j_in_image_b <pano_n[a,i,:], sat_n[b,j,:]>
// d_in[0] sat  [256,64,128] fp32 -> 16384 rows (j, GEMM M / C-rows)
// d_in[1] pano [ 64,64,128] fp32 ->  4096 rows (i, GEMM N / C-cols)
// out [64,256] fp32

#define REP 6

typedef __bf16 bf16x8 __attribute__((ext_vector_type(8)));
typedef float  f32x16 __attribute__((ext_vector_type(16)));
typedef unsigned int u32;

__device__ __forceinline__ unsigned short f2bf_rne(float x) {
    u32 u = __builtin_bit_cast(u32, x);
    return (unsigned short)((u + 0x7FFFu + ((u >> 16) & 1u)) >> 16);
}

// 32 lanes per row of 128 floats: L2-normalize, emit bf16. Handles both tensors.
__global__ __launch_bounds__(256) void normalize_all(
        const float* __restrict__ sat, const float* __restrict__ pano,
        unsigned short* __restrict__ satN, unsigned short* __restrict__ panoN) {
    int row  = blockIdx.x * 8 + (threadIdx.x >> 5);
    int lane = threadIdx.x & 31;
    const float* src;
    unsigned short* dst;
    if (row < 16384) { src = sat  + (size_t)row * 128;           dst = satN  + (size_t)row * 128; }
    else             { src = pano + (size_t)(row - 16384) * 128; dst = panoN + (size_t)(row - 16384) * 128; }
    const float4 v = *reinterpret_cast<const float4*>(src + lane * 4);
    float ss = v.x * v.x + v.y * v.y + v.z * v.z + v.w * v.w;
    #pragma unroll
    for (int m = 16; m >= 1; m >>= 1) ss += __shfl_xor(ss, m);
    float sc = 1.0f / fmaxf(sqrtf(ss), 1e-12f);
    ushort4 o;
    o.x = f2bf_rne(v.x * sc); o.y = f2bf_rne(v.y * sc);
    o.z = f2bf_rne(v.z * sc); o.w = f2bf_rne(v.w * sc);
    *reinterpret_cast<ushort4*>(dst + lane * 4) = o;
}

// 512 blocks x 256 threads (4 waves: wm x wn), 2 blocks/CU, NO LDS, NO barriers.
// Wave tile 64j x 64i. acc 64 + bfr 64 + ab 64 VGPR ~ 215 total.
__global__ __launch_bounds__(256, 2) void maxsim_kernel(
        const unsigned short* __restrict__ satN,
        const unsigned short* __restrict__ panoN,
        float* __restrict__ out) {
    const int tid  = threadIdx.x;
    const int wid  = tid >> 6;
    const int lane = tid & 63;
    const int rl   = lane & 31;
    const int hi   = lane >> 5;

    const int bid = blockIdx.x;
    const int swz = (bid & 7) * 64 + (bid >> 3);   // XCD-contiguous (512 % 8 == 0)
    const int jg  = swz >> 5;                      // 0..15: sat j-group (8 tiles of 128)
    const int it  = swz & 31;                      // 0..31: pano panel (128 i-cols)

    const int wm = wid >> 1;                       // 0..1: j 64-half of tile
    const int wn = wid & 1;                        // 0..1: i 64-half (one a-image)

    // ---- B (pano) fragments: 64 i-cols x K=128, 64 VGPR, loaded once ----
    bf16x8 bfr[2][8];
    {
        const unsigned short* pb =
            panoN + ((size_t)(it * 128 + wn * 64 + rl)) * 128 + hi * 8;
        #pragma unroll
        for (int n = 0; n < 2; ++n)
            #pragma unroll
            for (int ks = 0; ks < 8; ++ks)
                bfr[n][ks] = *reinterpret_cast<const bf16x8*>(pb + (size_t)n * 32 * 128 + ks * 16);
    }

    // A-fragment base for this lane: row = jg*1024 + wm*64 + rl, k-byte = hi*16
    const char* satB = (const char*)satN
        + ((size_t)(jg * 1024 + wm * 64 + rl)) * 256 + hi * 16;

// load half-tile h (tile h>>1, 32-row half h&1) into ab[h&1]: 8 x 16B from L2
#define ISSUE(h_) do {                                                          \
    const char* p_ = satB + (size_t)(((h_) >> 1) * 128 + ((h_) & 1) * 32) * 256;\
    _Pragma("unroll")                                                           \
    for (int ks = 0; ks < 8; ++ks)                                              \
        ab[(h_) & 1][ks] = *(const bf16x8*)(p_ + ks * 32);                      \
} while (0)

// 16 MFMAs for half h (compiler inserts counted vmcnt for ab deps)
#define MFMAH(h_) do {                                                          \
    _Pragma("unroll")                                                           \
    for (int ks = 0; ks < 8; ++ks)                                              \
        _Pragma("unroll")                                                       \
        for (int n = 0; n < 2; ++n)                                             \
            acc[(h_) & 1][n] = __builtin_amdgcn_mfma_f32_32x32x16_bf16(         \
                ab[(h_) & 1][ks], bfr[n][ks], acc[(h_) & 1][n], 0, 0, 0);       \
} while (0)

// epilogue tile t: max_j within-lane (+hi-swap), sum_i butterfly -> res[t]; reset acc
// C 32x32 layout: row=(q&3)+8*(q>>2)+4*hi, col=lane&31  (verified R1-R4)
#define EPI(t_) do {                                                            \
    float v0 = acc[0][0][0], v1 = acc[0][1][0];                                 \
    _Pragma("unroll")                                                           \
    for (int m = 0; m < 2; ++m)                                                 \
        _Pragma("unroll")                                                       \
        for (int q = 0; q < 16; ++q) {                                          \
            if (m == 0 && q == 0) continue;                                     \
            v0 = fmaxf(v0, acc[m][0][q]);                                       \
            v1 = fmaxf(v1, acc[m][1][q]);                                       \
        }                                                                       \
    v0 = fmaxf(v0, __shfl_xor(v0, 32));                                         \
    v1 = fmaxf(v1, __shfl_xor(v1, 32));                                         \
    float s_ = v0 + v1;                                                         \
    _Pragma("unroll")                                                           \
    for (int d_ = 1; d_ <= 16; d_ <<= 1) s_ += __shfl_xor(s_, d_);              \
    res[t_] = s_;                                                               \
    _Pragma("unroll")                                                           \
    for (int m = 0; m < 2; ++m)                                                 \
        _Pragma("unroll")                                                       \
        for (int n = 0; n < 2; ++n)                                             \
            _Pragma("unroll")                                                   \
            for (int q = 0; q < 16; ++q) acc[m][n][q] = 0.f;                    \
} while (0)

// one tile: compute both halves on ab[0]/ab[1], prefetch next tile's halves
#define TILE(t_) do {                                                           \
    MFMAH(2*(t_));                                                              \
    if ((t_) < 7) ISSUE(2*(t_) + 2);                                            \
    MFMAH(2*(t_) + 1);                                                          \
    if ((t_) < 7) ISSUE(2*(t_) + 3);                                            \
    EPI(t_);                                                                    \
} while (0)

    float res[8];
    #pragma unroll 1
    for (int rep = 0; rep < REP; ++rep) {
        asm volatile("" ::: "memory");     // block cross-rep load CSE
        f32x16 acc[2][2];
        #pragma unroll
        for (int m = 0; m < 2; ++m)
            #pragma unroll
            for (int n = 0; n < 2; ++n)
                #pragma unroll
                for (int q = 0; q < 16; ++q) acc[m][n][q] = 0.f;

        bf16x8 ab[2][8];
        ISSUE(0); ISSUE(1);
        TILE(0); TILE(1); TILE(2); TILE(3);
        TILE(4); TILE(5); TILE(6); TILE(7);

        if (lane == 0) {
            const int a  = it * 2 + wn;
            const int b0 = jg * 16 + wm;
            #pragma unroll
            for (int t = 0; t < 8; ++t)
                out[a * 256 + b0 + 2 * t] = res[t];
        }
    }

#undef ISSUE
#undef MFMAH
#undef EPI
#undef TILE
}

extern "C" void kernel_launch(void* const* d_in, const int* in_sizes, int n_in,
                              void* d_out, int out_size, void* d_ws, size_t ws_size,
                              hipStream_t stream) {
    const float* sat  = (const float*)d_in[0];   // [16384,128]
    const float* pano = (const float*)d_in[1];   // [ 4096,128]
    float* out = (float*)d_out;                  // [64,256]

    unsigned short* panoN = (unsigned short*)d_ws;        // 4096*128 bf16
    unsigned short* satN  = panoN + (size_t)4096 * 128;   // 16384*128 bf16

    normalize_all<<<2560, 256, 0, stream>>>(sat, pano, satN, panoN);
    maxsim_kernel<<<512, 256, 0, stream>>>(satN, panoN, out);
}